// Round 6
// baseline (190.876 us; speedup 1.0000x reference)
//
#include <hip/hip_runtime.h>
#include <math.h>

// B=4 graphs, N=256 nodes/graph (128+128), F=256, L=3 layers.
// 8 launches: prep + 3x{hqk, al} + fin. Kernel boundaries provide cross-XCD
// coherence (round-3 showed in-kernel atomic barriers thrash L2 on 8 XCDs).
// GEMMs: bf16 MFMA 16x16x32, one wave per 16x16 tile, operands L2-resident.
//
// Key identities:
//   qs = (x@W).q = x.(W@q)  -> Wq/Wk precomputed in prep; qs/ks row-local.
//   msg1 rows are dst-tile-local -> attn GEMM + lin GEMM fused, msg1 in LDS.
//
// x-buffer chain (layer i reads xs[i], writes xs[i+1] iff do_bn):
//   layer0 reads x0 (no write) / layer1 reads x0 writes x1 /
//   layer2 reads x1 writes x0 / fin reads x0.

typedef __attribute__((ext_vector_type(8))) short short8;   // 8 bf16
typedef __attribute__((ext_vector_type(4))) float f32x4;
typedef unsigned short u16;
typedef unsigned int   u32;

__device__ __forceinline__ u16 f2bf(float f) {
    union { float f; u32 u; } v; v.f = f;
    u32 r = v.u + 0x7fffu + ((v.u >> 16) & 1u);     // RNE
    return (u16)(r >> 16);
}
__device__ __forceinline__ short8 ld8(const u16* p) {
    return __builtin_bit_cast(short8, *(const int4*)p);
}

// ---- P0: pack x + transpose conv_w -> Wt + cast lin_w + Wq/Wk dots ---------
__global__ __launch_bounds__(256) void k_prep(
    const float* __restrict__ d0, const float* __restrict__ d1,
    const float* __restrict__ conv_w, const float* __restrict__ lin_w,
    const float* __restrict__ conv_q, const float* __restrict__ conv_k,
    float* __restrict__ x, u16* __restrict__ xb,
    u16* __restrict__ Wt, u16* __restrict__ lwb, float* __restrict__ wqk) {
    for (int i = blockIdx.x * 256 + threadIdx.x; i < 1051648; i += 262144) {
        if (i < 262144) {
            int node = i >> 8, f = i & 255, b = node >> 8, nl = node & 255;
            float v = (nl < 128) ? d0[b * 32768 + f * 128 + nl]
                                 : d1[b * 32768 + f * 128 + (nl - 128)];
            x[i] = v; xb[i] = f2bf(v);
        } else if (i < 655360) {
            int o = i - 262144;                     // 6 mats of 256x256
            int mat = o >> 16, rem = o & 65535, e = rem >> 8, f = rem & 255;
            Wt[o] = f2bf(conv_w[mat * 65536 + f * 256 + e]);
        } else if (i < 1048576) {
            int o = i - 655360;
            lwb[o] = f2bf(lin_w[o]);
        } else {
            int o = i - 1048576;                    // 0..3071
            int c2 = o >> 8;                        // layer*4 + rel*2 + qk
            int layer = c2 >> 2, rel = (c2 >> 1) & 1, qk = c2 & 1, f = o & 255;
            const float* vec  = (qk ? conv_k : conv_q) + layer * 256;
            const float* wrow = conv_w + (layer * 2 + rel) * 65536 + f * 256;
            float s = 0.f;
            #pragma unroll 4
            for (int e = 0; e < 256; e += 4) {
                float4 w4 = *(const float4*)&wrow[e];
                float4 v4 = *(const float4*)&vec[e];
                s += w4.x * v4.x + w4.y * v4.y + w4.z * v4.z + w4.w * v4.w;
            }
            wqk[layer * 1024 + (rel * 2 + qk) * 256 + f] = s;
        }
    }
}

// ---- K1: BN-apply(prev) + H-GEMM -> Ht + row-local qs/ks -------------------
// grid 256 = (64 m-tiles) x (4 e-groups); 256 thr (4 waves).
__global__ __launch_bounds__(256, 1) void k_hqk(
    const float* __restrict__ xprev, const float* __restrict__ msg2,
    const float* __restrict__ sums, const float* __restrict__ sumsq,
    const float* __restrict__ bw, const float* __restrict__ bb,
    const u16* __restrict__ cwt,                 // [2][256 e][256 f]
    const float* __restrict__ wqk_l,             // [4][256]: (rel*2+qk)
    float* __restrict__ xcur, u16* __restrict__ xb, u16* __restrict__ Ht,
    float* __restrict__ qkbuf,                   // [4][1024]
    int do_bn) {
    __shared__ __align__(16) u16 Asub[16 * 264];  // [16 nodes][256 f] bf16
    __shared__ __align__(16) float Xs[16 * 260];  // fp32 copy for qs/ks dots
    const int tid = threadIdx.x;
    const int mt = blockIdx.x >> 2, eg = blockIdx.x & 3;
    const int m0 = mt * 16;
    const int lane = tid & 63, widx = tid >> 6;
    const int row = lane & 15, kg = lane >> 4;

    float scale = 0.f, shift = 0.f;
    if (do_bn) {                                  // col = tid, redundant/block
        float s1 = 0.f, s2 = 0.f;
        #pragma unroll 8
        for (int c = 0; c < 64; ++c) { s1 += sums[c * 256 + tid]; s2 += sumsq[c * 256 + tid]; }
        float mu  = s1 * (1.f / 1024.f);
        float var = s2 * (1.f / 1024.f) - mu * mu;        // biased, as reference
        scale = bw[tid] * rsqrtf(var + 1e-5f);
        shift = bb[tid] - mu * scale;
    }
    #pragma unroll
    for (int r = 0; r < 16; ++r) {                // x_cur rows, col = tid
        int idx = (m0 + r) * 256 + tid;
        float v = xprev[idx];
        if (do_bn) v += msg2[idx] * scale + shift;
        u16 hb = f2bf(v);
        Asub[r * 264 + tid] = hb;
        Xs[r * 260 + tid] = v;
        if (do_bn && eg == 0) { xcur[idx] = v; xb[idx] = hb; }
    }
    __syncthreads();

    const int et = eg * 4 + widx, e0 = et * 16;   // e-tile 0..15
    const u16* B0 = cwt + (e0 + row) * 256 + kg * 8;
    const u16* B1 = B0 + 65536;
    const u16* Ap = &Asub[row * 264 + kg * 8];
    f32x4 acc0 = {0.f,0.f,0.f,0.f}, acc1 = {0.f,0.f,0.f,0.f};
    #pragma unroll
    for (int k0 = 0; k0 < 256; k0 += 32) {
        short8 a = ld8(Ap + k0);
        acc0 = __builtin_amdgcn_mfma_f32_16x16x32_bf16(a, ld8(B0 + k0), acc0, 0, 0, 0);
        acc1 = __builtin_amdgcn_mfma_f32_16x16x32_bf16(a, ld8(B1 + k0), acc1, 0, 0, 0);
    }
    // D: col(lane&15)=e, row(kg*4+c)=node -> store transposed Ht[r][e][node]
    ushort4 o0, o1;
    o0.x = f2bf(acc0[0]); o0.y = f2bf(acc0[1]); o0.z = f2bf(acc0[2]); o0.w = f2bf(acc0[3]);
    o1.x = f2bf(acc1[0]); o1.y = f2bf(acc1[1]); o1.z = f2bf(acc1[2]); o1.w = f2bf(acc1[3]);
    *(ushort4*)(Ht + (e0 + row) * 1024 + m0 + kg * 4) = o0;
    *(ushort4*)(Ht + 262144 + (e0 + row) * 1024 + m0 + kg * 4) = o1;

    // qs/ks for this block's 16 rows: wave widx handles combo widx (fp32 exact)
    if (eg == 0) {
        const float* wv = wqk_l + widx * 256;
        float4 w4 = *(const float4*)&wv[lane * 4];
        #pragma unroll
        for (int r = 0; r < 16; ++r) {
            float4 xv = *(const float4*)&Xs[r * 260 + lane * 4];
            float s = xv.x * w4.x + xv.y * w4.y + xv.z * w4.z + xv.w * w4.w;
            s += __shfl_xor(s, 32); s += __shfl_xor(s, 16); s += __shfl_xor(s, 8);
            s += __shfl_xor(s, 4);  s += __shfl_xor(s, 2);  s += __shfl_xor(s, 1);
            if (lane == 0) qkbuf[widx * 1024 + m0 + r] = s;
        }
    }
}

// ---- K2: alpha (LDS) + attn GEMM (msg1 in LDS) + lin GEMM + BN partials ----
// grid 64 (dst-tiles), 512 thr (8 waves).
__global__ __launch_bounds__(512, 1) void k_al(
    const float* __restrict__ qkbuf, const u16* __restrict__ Ht,
    const float* __restrict__ cb,
    const u16* __restrict__ xb, const u16* __restrict__ lwp,
    const float* __restrict__ lb,
    float* __restrict__ msg2, float* __restrict__ sums, float* __restrict__ sumsq) {
    __shared__ __align__(16) u16 Atile[16 * 264]; // alpha bf16 [16 dst][256 src]
    __shared__ __align__(16) u16 M1[16 * 264];    // msg1 bf16 [16 dst][256 e]
    __shared__ float ksl[2][256];
    __shared__ float qsl[2][16];
    __shared__ __align__(16) float T[8][16 * 20];
    const int tid = threadIdx.x;
    const int mt = blockIdx.x;
    const int m0 = mt * 16;
    const int g = mt >> 4, a = (mt >> 3) & 1;
    const int lane = tid & 63, w = tid >> 6;
    const int row = lane & 15, kg = lane >> 4;

    {   // stage qs/ks
        int rel = tid >> 8, s = tid & 255;
        ksl[rel][s] = qkbuf[(rel * 2 + 1) * 1024 + g * 256 + s];
    }
    if (tid < 32) {
        int rel = tid >> 4, r = tid & 15;
        qsl[rel][r] = qkbuf[(rel * 2) * 1024 + m0 + r];
    }
    __syncthreads();
    if (tid < 256) {  // softmax: thread = (dst r = tid>>4, src chunk j = tid&15)
        const int r = tid >> 4, j = tid & 15;
        const int dl = (m0 + r) & 255;
        const int s0 = j * 16;
        const int rel = ((s0 >> 7) == a) ? 0 : 1; // chunk never crosses 128
        float qv = qsl[rel][r];
        float l[16], mx = -1e30f;
        #pragma unroll
        for (int i2 = 0; i2 < 16; ++i2) {
            float v = qv + ksl[rel][s0 + i2];
            v = (v >= 0.f) ? v : 0.2f * v;        // leaky_relu 0.2
            if (s0 + i2 == dl) v = -1e30f;        // no self-loop
            l[i2] = v; mx = fmaxf(mx, v);
        }
        #pragma unroll
        for (int off = 1; off < 16; off <<= 1) mx = fmaxf(mx, __shfl_xor(mx, off));
        float s = 0.f;
        #pragma unroll
        for (int i2 = 0; i2 < 16; ++i2) { l[i2] = __expf(l[i2] - mx); s += l[i2]; }
        #pragma unroll
        for (int off = 1; off < 16; off <<= 1) s += __shfl_xor(s, off);
        float inv = 1.f / (s + 1e-16f);
        #pragma unroll
        for (int i2 = 0; i2 < 16; i2 += 2) {
            u32 p = (u32)f2bf(l[i2] * inv) | ((u32)f2bf(l[i2 + 1] * inv) << 16);
            *(u32*)&Atile[r * 264 + s0 + i2] = p;
        }
    }
    __syncthreads();
    // attn GEMM: msg1[dst][e] = relu(alpha @ H_sel + cb) -> LDS only
    const u16* Ap = &Atile[row * 264 + kg * 8];
    #pragma unroll
    for (int it = 0; it < 2; ++it) {
        const int e0 = (w + it * 8) * 16;
        f32x4 acc = {0.f,0.f,0.f,0.f};
        #pragma unroll
        for (int k0 = 0; k0 < 256; k0 += 32) {
            const int rel = (((k0 >> 7) & 1) == a) ? 0 : 1;   // tile-uniform
            const u16* B = Ht + rel * 262144 + (e0 + row) * 1024 + g * 256 + k0 + kg * 8;
            acc = __builtin_amdgcn_mfma_f32_16x16x32_bf16(ld8(Ap + k0), ld8(B), acc, 0, 0, 0);
        }
        float bias = cb[e0 + row];
        #pragma unroll
        for (int c = 0; c < 4; ++c)   // D: col=e (e0+row), regs = dst (kg*4+c)
            M1[(kg * 4 + c) * 264 + e0 + row] = f2bf(fmaxf(acc[c] + bias, 0.f));
    }
    __syncthreads();
    // lin GEMM: msg2 = [xb | msg1] @ lwp^T + lb ; BN column partials
    #pragma unroll
    for (int it = 0; it < 2; ++it) {
        const int n0 = (w + it * 8) * 16;
        const u16* A0 = xb + (m0 + row) * 256 + kg * 8;
        const u16* A1 = &M1[row * 264 + kg * 8];
        const u16* B  = lwp + (n0 + row) * 512 + kg * 8;
        f32x4 acc = {0.f,0.f,0.f,0.f};
        #pragma unroll
        for (int k0 = 0; k0 < 512; k0 += 32) {
            short8 av = (k0 < 256) ? ld8(A0 + k0) : ld8(A1 + (k0 - 256));
            acc = __builtin_amdgcn_mfma_f32_16x16x32_bf16(av, ld8(B + k0), acc, 0, 0, 0);
        }
        float bias = lb[n0 + row];
        float v0 = acc[0] + bias, v1 = acc[1] + bias, v2 = acc[2] + bias, v3 = acc[3] + bias;
        float s1 = v0 + v1 + v2 + v3;
        float s2 = v0 * v0 + v1 * v1 + v2 * v2 + v3 * v3;
        s1 += __shfl_xor(s1, 16); s1 += __shfl_xor(s1, 32);
        s2 += __shfl_xor(s2, 16); s2 += __shfl_xor(s2, 32);
        if (lane < 16) {          // lane = n col within tile
            sums [mt * 256 + n0 + lane] = s1;
            sumsq[mt * 256 + n0 + lane] = s2;
        }
        float* Tw = &T[w][0];     // per-wave slice: wave-local, no barrier
        Tw[(kg * 4 + 0) * 20 + row] = v0;
        Tw[(kg * 4 + 1) * 20 + row] = v1;
        Tw[(kg * 4 + 2) * 20 + row] = v2;
        Tw[(kg * 4 + 3) * 20 + row] = v3;
        float4 vv = *(float4*)&Tw[row * 20 + kg * 4];
        *(float4*)(msg2 + (m0 + row) * 256 + n0 + kg * 4) = vv;
    }
}

// ---- K_fin: final BN + residual + unpack to [B,F,N0]|[B,F,N1] --------------
__global__ __launch_bounds__(256) void k_fin(
    const float* __restrict__ x2, const float* __restrict__ msg2,
    const float* __restrict__ sums, const float* __restrict__ sumsq,
    const float* __restrict__ bw, const float* __restrict__ bb,
    float* __restrict__ out) {
    const int blk = blockIdx.x, t = threadIdx.x;
    float s1 = 0.f, s2 = 0.f;
    #pragma unroll 8
    for (int c = 0; c < 64; ++c) { s1 += sums[c * 256 + t]; s2 += sumsq[c * 256 + t]; }
    float mu  = s1 * (1.f / 1024.f);
    float var = s2 * (1.f / 1024.f) - mu * mu;
    float scale = bw[t] * rsqrtf(var + 1e-5f);
    float shift = bb[t] - mu * scale;
    #pragma unroll
    for (int j = 0; j < 4; ++j) {
        int node = blk * 4 + j;
        int idx = node * 256 + t;
        float v = x2[idx] + msg2[idx] * scale + shift;
        int b = node >> 8, nl = node & 255, half = nl >> 7, n = nl & 127;
        out[half * 131072 + b * 32768 + t * 128 + n] = v;
    }
}

// ----------------------------------------------------------------------------
extern "C" void kernel_launch(void* const* d_in, const int* in_sizes, int n_in,
                              void* d_out, int out_size, void* d_ws, size_t ws_size,
                              hipStream_t stream) {
    const float* desc0  = (const float*)d_in[0];
    const float* desc1  = (const float*)d_in[1];
    const float* conv_w = (const float*)d_in[2];
    const float* conv_q = (const float*)d_in[3];
    const float* conv_k = (const float*)d_in[4];
    const float* conv_b = (const float*)d_in[5];
    const float* lin_w  = (const float*)d_in[6];
    const float* lin_b  = (const float*)d_in[7];
    const float* bn_w   = (const float*)d_in[8];
    const float* bn_b   = (const float*)d_in[9];
    float* out = (float*)d_out;

    char* p = (char*)d_ws;
    float* x0     = (float*)p; p += 1048576;
    float* x1     = (float*)p; p += 1048576;
    u16*   xb     = (u16*)p;   p += 524288;
    u16*   Wt     = (u16*)p;   p += 786432;    // [3][2][256e][256f]
    u16*   lwb    = (u16*)p;   p += 786432;
    u16*   Ht     = (u16*)p;   p += 1048576;   // [2][256e][1024node]
    float* wqk    = (float*)p; p += 12288;     // [3][4][256]
    float* qkbuf  = (float*)p; p += 16384;     // [4][1024]
    float* msg2   = (float*)p; p += 1048576;
    float* sums   = (float*)p; p += 65536;     // [64][256]
    float* sumsq  = (float*)p; p += 65536;

    k_prep<<<1024, 256, 0, stream>>>(desc0, desc1, conv_w, lin_w, conv_q, conv_k,
                                     x0, xb, Wt, lwb, wqk);

    // layer i reads xs[i]; writes xs[i+1] only when do_bn (i>0).
    float* xs[4] = {x0, x0, x1, x0};
    for (int i = 0; i < 3; ++i) {
        const u16*   cwt = Wt + i * 131072;
        const u16*   lwp = lwb + i * 131072;
        const float* cb = conv_b + i * 256;
        const float* lb = lin_b + i * 256;
        const float* bwp = bn_w + (i ? (i - 1) * 256 : 0);   // prev-layer BN
        const float* bbp = bn_b + (i ? (i - 1) * 256 : 0);

        k_hqk<<<256, 256, 0, stream>>>(xs[i], msg2, sums, sumsq, bwp, bbp,
                                       cwt, wqk + i * 1024, xs[i + 1], xb, Ht,
                                       qkbuf, i > 0 ? 1 : 0);
        k_al<<<64, 512, 0, stream>>>(qkbuf, Ht, cb, xb, lwp, lb,
                                     msg2, sums, sumsq);
    }

    k_fin<<<256, 256, 0, stream>>>(xs[3], msg2, sums, sumsq,
                                   bn_w + 512, bn_b + 512, out);
}

// Round 7
// 175.940 us; speedup vs baseline: 1.0849x; 1.0849x over previous
//
#include <hip/hip_runtime.h>
#include <math.h>

// B=4 graphs, N=256 nodes (128+128)/graph, F=256, L=3 layers.
// 8 launches: prep1, prep2, (k_A,k_B)x2, k_A, k_fin — ALL 256-block grids.
//
// Algebra: msg1 = relu( y0@W0 + y1@W1 + cb ),  y_t[dst] = sum_{src in rel t} alpha*x[src]
//   -> no H materialization at all. qs/ks via qs = x.(W@q) (wqk precomputed).
// alpha needs only qkbuf (per-node dots) -> computed row-locally in k_B/prep2.
// y-GEMM B-operand needs x^T -> xbt maintained alongside xb.
// GEMM pattern (validated r5/r6): A,B^T both row-major k-contiguous, ld8 frags,
// mfma_16x16x32_bf16, D: n = n0+(lane&15), m = kg*4+reg.

typedef __attribute__((ext_vector_type(8))) short short8;   // 8 bf16
typedef __attribute__((ext_vector_type(4))) float f32x4;
typedef unsigned short u16;
typedef unsigned int   u32;

__device__ __forceinline__ u16 f2bf(float f) {
    union { float f; u32 u; } v; v.f = f;
    u32 r = v.u + 0x7fffu + ((v.u >> 16) & 1u);     // RNE
    return (u16)(r >> 16);
}
__device__ __forceinline__ short8 ld8(const u16* p) {
    return __builtin_bit_cast(short8, *(const int4*)p);
}

// ---- prep1: Wt = conv_w^T (bf16), lwb = bf16(lin_w), wqk = conv_w @ q/k ----
__global__ __launch_bounds__(256) void k_prep1(
    const float* __restrict__ conv_w, const float* __restrict__ lin_w,
    const float* __restrict__ conv_q, const float* __restrict__ conv_k,
    u16* __restrict__ Wt, u16* __restrict__ lwb, float* __restrict__ wqk) {
    for (int i = blockIdx.x * 256 + threadIdx.x; i < 789504; i += 262144) {
        if (i < 393216) {                           // 6 mats of 256x256
            int mat = i >> 16, rem = i & 65535, e = rem >> 8, f = rem & 255;
            Wt[i] = f2bf(conv_w[mat * 65536 + f * 256 + e]);
        } else if (i < 786432) {
            int o = i - 393216;
            lwb[o] = f2bf(lin_w[o]);
        } else {
            int o = i - 786432;                     // 0..3071
            int c2 = o >> 8;                        // layer*4 + rel*2 + qk
            int layer = c2 >> 2, rel = (c2 >> 1) & 1, qk = c2 & 1, f = o & 255;
            const float* vec  = (qk ? conv_k : conv_q) + layer * 256;
            const float* wrow = conv_w + (layer * 2 + rel) * 65536 + f * 256;
            float s = 0.f;
            #pragma unroll 4
            for (int e = 0; e < 256; e += 4) {
                float4 w4 = *(const float4*)&wrow[e];
                float4 v4 = *(const float4*)&vec[e];
                s += w4.x * v4.x + w4.y * v4.y + w4.z * v4.z + w4.w * v4.w;
            }
            wqk[layer * 1024 + (rel * 2 + qk) * 256 + f] = s;
        }
    }
}

// ---- prep2: pack x/xb/xbt + qkbuf for layer 0 (needs wqk -> after prep1) ---
// 256 blocks x 256 thr; block owns 4 nodes.
__global__ __launch_bounds__(256) void k_prep2(
    const float* __restrict__ d0, const float* __restrict__ d1,
    const float* __restrict__ wqk0, float* __restrict__ x, u16* __restrict__ xb,
    u16* __restrict__ xbt, float* __restrict__ qkbuf) {
    __shared__ __align__(16) float Xs[4][260];
    const int blk = blockIdx.x, t = threadIdx.x;
    u16 col[4];
    #pragma unroll
    for (int r = 0; r < 4; ++r) {
        int node = blk * 4 + r, b = node >> 8, nl = node & 255;
        float v = (nl < 128) ? d0[b * 32768 + t * 128 + nl]
                             : d1[b * 32768 + t * 128 + (nl - 128)];
        x[node * 256 + t] = v;
        u16 h = f2bf(v);
        xb[node * 256 + t] = h;
        col[r] = h;
        Xs[r][t] = v;
    }
    ushort4 cv = {col[0], col[1], col[2], col[3]};
    *(ushort4*)(xbt + t * 1024 + blk * 4) = cv;     // xbt[f][node], 4 nodes
    __syncthreads();
    const int w = t >> 6, lane = t & 63;            // wave w -> node blk*4+w
    float4 xv = *(const float4*)&Xs[w][lane * 4];
    #pragma unroll
    for (int combo = 0; combo < 4; ++combo) {
        float4 q4 = *(const float4*)&wqk0[combo * 256 + lane * 4];
        float s = xv.x * q4.x + xv.y * q4.y + xv.z * q4.z + xv.w * q4.w;
        s += __shfl_xor(s, 32); s += __shfl_xor(s, 16); s += __shfl_xor(s, 8);
        s += __shfl_xor(s, 4);  s += __shfl_xor(s, 2);  s += __shfl_xor(s, 1);
        if (lane == 0) qkbuf[combo * 1024 + blk * 4 + w] = s;
    }
}

// ---- k_A: alpha -> y -> msg1 -> lin (+BN partials), all LDS-resident -------
// grid 256 = (64 dst-tiles) x (4 ng lin-output groups); 256 thr (4 waves).
__global__ __launch_bounds__(256, 1) void k_A(
    const float* __restrict__ qkbuf, const u16* __restrict__ xb,
    const u16* __restrict__ xbt, const u16* __restrict__ Wt_l,  // [2][256e][256f]
    const u16* __restrict__ lwp, const float* __restrict__ cb,
    const float* __restrict__ lb, float* __restrict__ msg2,
    float* __restrict__ sums, float* __restrict__ sumsq) {
    __shared__ __align__(16) u16 AM[16 * 264];      // alpha, then msg1 (aliased)
    __shared__ __align__(16) u16 Y0[16 * 264];      // y rel0 [dst][f]
    __shared__ __align__(16) u16 Y1[16 * 264];
    __shared__ float ksl[2][256];
    __shared__ float qsl[2][16];
    __shared__ __align__(16) float T[4][16 * 20];
    const int tid = threadIdx.x;
    const int mt = blockIdx.x >> 2, ng = blockIdx.x & 3;
    const int m0 = mt * 16, g = mt >> 4, a = (mt >> 3) & 1;
    const int lane = tid & 63, w = tid >> 6;
    const int row = lane & 15, kg = lane >> 4;

    ksl[0][tid] = qkbuf[1 * 1024 + g * 256 + tid];  // combo rel*2+1 = k-score
    ksl[1][tid] = qkbuf[3 * 1024 + g * 256 + tid];
    if (tid < 32) {
        int rel = tid >> 4, r = tid & 15;
        qsl[rel][r] = qkbuf[(rel * 2) * 1024 + m0 + r];
    }
    __syncthreads();
    {   // softmax: thread = (dst r = tid>>4, src chunk j = tid&15)
        const int r = tid >> 4, j = tid & 15;
        const int dl = (m0 + r) & 255;
        const int s0 = j * 16;
        const int rel = ((s0 >> 7) == a) ? 0 : 1;   // chunk never crosses 128
        float qv = qsl[rel][r];
        float l[16], mx = -1e30f;
        #pragma unroll
        for (int i2 = 0; i2 < 16; ++i2) {
            float v = qv + ksl[rel][s0 + i2];
            v = (v >= 0.f) ? v : 0.2f * v;          // leaky_relu 0.2
            if (s0 + i2 == dl) v = -1e30f;          // no self-loop
            l[i2] = v; mx = fmaxf(mx, v);
        }
        #pragma unroll
        for (int off = 1; off < 16; off <<= 1) mx = fmaxf(mx, __shfl_xor(mx, off));
        float s = 0.f;
        #pragma unroll
        for (int i2 = 0; i2 < 16; ++i2) { l[i2] = __expf(l[i2] - mx); s += l[i2]; }
        #pragma unroll
        for (int off = 1; off < 16; off <<= 1) s += __shfl_xor(s, off);
        float inv = 1.f / (s + 1e-16f);
        #pragma unroll
        for (int i2 = 0; i2 < 16; i2 += 2) {
            u32 p = (u32)f2bf(l[i2] * inv) | ((u32)f2bf(l[i2 + 1] * inv) << 16);
            *(u32*)&AM[r * 264 + s0 + i2] = p;
        }
    }
    __syncthreads();
    // y GEMM: y_t[dst][f] = sum_{src in rel t} alpha * x[src][f]; B^T = xbt
    {
        const u16* Ap = &AM[row * 264 + kg * 8];
        #pragma unroll
        for (int it = 0; it < 4; ++it) {
            const int f0 = (w * 4 + it) * 16;
            f32x4 a0 = {0.f,0.f,0.f,0.f}, a1 = {0.f,0.f,0.f,0.f};
            const u16* Bp = xbt + (f0 + row) * 1024 + g * 256 + kg * 8;
            #pragma unroll
            for (int k0 = 0; k0 < 256; k0 += 32) {
                short8 av = ld8(Ap + k0);
                short8 bv = ld8(Bp + k0);
                if (((k0 >> 7) == a))
                    a0 = __builtin_amdgcn_mfma_f32_16x16x32_bf16(av, bv, a0, 0, 0, 0);
                else
                    a1 = __builtin_amdgcn_mfma_f32_16x16x32_bf16(av, bv, a1, 0, 0, 0);
            }
            #pragma unroll
            for (int c = 0; c < 4; ++c) {           // m=dst=kg*4+c, n=f=f0+row
                Y0[(kg * 4 + c) * 264 + f0 + row] = f2bf(a0[c]);
                Y1[(kg * 4 + c) * 264 + f0 + row] = f2bf(a1[c]);
            }
        }
    }
    __syncthreads();                                 // Y ready; alpha dead
    // msg1 GEMM: msg1[dst][e] = relu(Y0@W0 + Y1@W1 + cb) -> AM (aliased)
    #pragma unroll
    for (int it = 0; it < 4; ++it) {
        const int e0 = (w * 4 + it) * 16;
        f32x4 acc = {0.f,0.f,0.f,0.f};
        const u16* B0 = Wt_l + (e0 + row) * 256 + kg * 8;
        #pragma unroll
        for (int k0 = 0; k0 < 256; k0 += 32)
            acc = __builtin_amdgcn_mfma_f32_16x16x32_bf16(
                ld8(&Y0[row * 264 + k0 + kg * 8]), ld8(B0 + k0), acc, 0, 0, 0);
        const u16* B1 = B0 + 65536;
        #pragma unroll
        for (int k0 = 0; k0 < 256; k0 += 32)
            acc = __builtin_amdgcn_mfma_f32_16x16x32_bf16(
                ld8(&Y1[row * 264 + k0 + kg * 8]), ld8(B1 + k0), acc, 0, 0, 0);
        float bias = cb[e0 + row];
        #pragma unroll
        for (int c = 0; c < 4; ++c)
            AM[(kg * 4 + c) * 264 + e0 + row] = f2bf(fmaxf(acc[c] + bias, 0.f));
    }
    __syncthreads();                                 // msg1 ready
    // lin GEMM: msg2 = [xb | msg1] @ lw^T + lb ; BN column partials
    {
        const int n0 = ng * 64 + w * 16;
        const u16* A0 = xb + (m0 + row) * 256 + kg * 8;
        const u16* A1 = &AM[row * 264 + kg * 8];
        const u16* B  = lwp + (n0 + row) * 512 + kg * 8;
        f32x4 acc = {0.f,0.f,0.f,0.f};
        #pragma unroll
        for (int k0 = 0; k0 < 512; k0 += 32) {
            short8 av = (k0 < 256) ? ld8(A0 + k0) : ld8(A1 + (k0 - 256));
            acc = __builtin_amdgcn_mfma_f32_16x16x32_bf16(av, ld8(B + k0), acc, 0, 0, 0);
        }
        float bias = lb[n0 + row];
        float v0 = acc[0] + bias, v1 = acc[1] + bias, v2 = acc[2] + bias, v3 = acc[3] + bias;
        float s1 = v0 + v1 + v2 + v3;
        float s2 = v0 * v0 + v1 * v1 + v2 * v2 + v3 * v3;
        s1 += __shfl_xor(s1, 16); s1 += __shfl_xor(s1, 32);
        s2 += __shfl_xor(s2, 16); s2 += __shfl_xor(s2, 32);
        if (lane < 16) {
            sums [mt * 256 + n0 + lane] = s1;
            sumsq[mt * 256 + n0 + lane] = s2;
        }
        float* Tw = &T[w][0];                        // wave-local transpose
        Tw[(kg * 4 + 0) * 20 + row] = v0;
        Tw[(kg * 4 + 1) * 20 + row] = v1;
        Tw[(kg * 4 + 2) * 20 + row] = v2;
        Tw[(kg * 4 + 3) * 20 + row] = v3;
        float4 vv = *(float4*)&Tw[row * 20 + kg * 4];
        *(float4*)(msg2 + (m0 + row) * 256 + n0 + kg * 4) = vv;
    }
}

// ---- k_B: BN reduce+apply (in-place x) + xb/xbt refresh + next-layer qk ----
// 256 blocks x 256 thr; block owns 4 nodes.
__global__ __launch_bounds__(256) void k_B(
    float* __restrict__ x, const float* __restrict__ msg2,
    const float* __restrict__ sums, const float* __restrict__ sumsq,
    const float* __restrict__ bw, const float* __restrict__ bb,
    const float* __restrict__ wqk_next,
    u16* __restrict__ xb, u16* __restrict__ xbt, float* __restrict__ qkbuf) {
    __shared__ __align__(16) float Xs[4][260];
    const int blk = blockIdx.x, t = threadIdx.x;
    float s1 = 0.f, s2 = 0.f;
    #pragma unroll 8
    for (int c = 0; c < 64; ++c) { s1 += sums[c * 256 + t]; s2 += sumsq[c * 256 + t]; }
    float mu  = s1 * (1.f / 1024.f);
    float var = s2 * (1.f / 1024.f) - mu * mu;       // biased, as reference
    float scale = bw[t] * rsqrtf(var + 1e-5f);
    float shift = bb[t] - mu * scale;
    u16 col[4];
    #pragma unroll
    for (int r = 0; r < 4; ++r) {
        int idx = (blk * 4 + r) * 256 + t;
        float v = x[idx] + msg2[idx] * scale + shift;
        x[idx] = v;
        u16 h = f2bf(v);
        xb[idx] = h;
        col[r] = h;
        Xs[r][t] = v;
    }
    ushort4 cv = {col[0], col[1], col[2], col[3]};
    *(ushort4*)(xbt + t * 1024 + blk * 4) = cv;
    __syncthreads();
    const int w = t >> 6, lane = t & 63;
    float4 xv = *(const float4*)&Xs[w][lane * 4];
    #pragma unroll
    for (int combo = 0; combo < 4; ++combo) {
        float4 q4 = *(const float4*)&wqk_next[combo * 256 + lane * 4];
        float s = xv.x * q4.x + xv.y * q4.y + xv.z * q4.z + xv.w * q4.w;
        s += __shfl_xor(s, 32); s += __shfl_xor(s, 16); s += __shfl_xor(s, 8);
        s += __shfl_xor(s, 4);  s += __shfl_xor(s, 2);  s += __shfl_xor(s, 1);
        if (lane == 0) qkbuf[combo * 1024 + blk * 4 + w] = s;
    }
}

// ---- k_fin: final BN + residual + unpack to [B,F,N0]|[B,F,N1] --------------
__global__ __launch_bounds__(256) void k_fin(
    const float* __restrict__ x2, const float* __restrict__ msg2,
    const float* __restrict__ sums, const float* __restrict__ sumsq,
    const float* __restrict__ bw, const float* __restrict__ bb,
    float* __restrict__ out) {
    const int blk = blockIdx.x, t = threadIdx.x;
    float s1 = 0.f, s2 = 0.f;
    #pragma unroll 8
    for (int c = 0; c < 64; ++c) { s1 += sums[c * 256 + t]; s2 += sumsq[c * 256 + t]; }
    float mu  = s1 * (1.f / 1024.f);
    float var = s2 * (1.f / 1024.f) - mu * mu;
    float scale = bw[t] * rsqrtf(var + 1e-5f);
    float shift = bb[t] - mu * scale;
    #pragma unroll
    for (int j = 0; j < 4; ++j) {
        int node = blk * 4 + j;
        int idx = node * 256 + t;
        float v = x2[idx] + msg2[idx] * scale + shift;
        int b = node >> 8, nl = node & 255, half = nl >> 7, n = nl & 127;
        out[half * 131072 + b * 32768 + t * 128 + n] = v;
    }
}

// ----------------------------------------------------------------------------
extern "C" void kernel_launch(void* const* d_in, const int* in_sizes, int n_in,
                              void* d_out, int out_size, void* d_ws, size_t ws_size,
                              hipStream_t stream) {
    const float* desc0  = (const float*)d_in[0];
    const float* desc1  = (const float*)d_in[1];
    const float* conv_w = (const float*)d_in[2];
    const float* conv_q = (const float*)d_in[3];
    const float* conv_k = (const float*)d_in[4];
    const float* conv_b = (const float*)d_in[5];
    const float* lin_w  = (const float*)d_in[6];
    const float* lin_b  = (const float*)d_in[7];
    const float* bn_w   = (const float*)d_in[8];
    const float* bn_b   = (const float*)d_in[9];
    float* out = (float*)d_out;

    char* p = (char*)d_ws;
    float* x      = (float*)p; p += 1048576;   // [1024][256] fp32 (in-place)
    u16*   xb     = (u16*)p;   p += 524288;    // [1024][256] bf16
    u16*   xbt    = (u16*)p;   p += 524288;    // [256 f][1024 node] bf16
    u16*   Wt     = (u16*)p;   p += 786432;    // [3][2][256e][256f]
    u16*   lwb    = (u16*)p;   p += 786432;    // [3][256][512]
    float* wqk    = (float*)p; p += 12288;     // [3][4][256]
    float* qkbuf  = (float*)p; p += 16384;     // [4][1024]
    float* msg2   = (float*)p; p += 1048576;   // [1024][256] fp32
    float* sums   = (float*)p; p += 65536;     // [64][256]
    float* sumsq  = (float*)p; p += 65536;

    k_prep1<<<1024, 256, 0, stream>>>(conv_w, lin_w, conv_q, conv_k, Wt, lwb, wqk);
    k_prep2<<<256, 256, 0, stream>>>(desc0, desc1, wqk, x, xb, xbt, qkbuf);

    for (int i = 0; i < 3; ++i) {
        k_A<<<256, 256, 0, stream>>>(qkbuf, xb, xbt, Wt + i * 131072,
                                     lwb + i * 131072, conv_b + i * 256,
                                     lin_b + i * 256, msg2, sums, sumsq);
        if (i < 2)
            k_B<<<256, 256, 0, stream>>>(x, msg2, sums, sumsq,
                                         bn_w + i * 256, bn_b + i * 256,
                                         wqk + (i + 1) * 1024, xb, xbt, qkbuf);
    }

    k_fin<<<256, 256, 0, stream>>>(x, msg2, sums, sumsq,
                                   bn_w + 512, bn_b + 512, out);
}

// Round 8
// 167.988 us; speedup vs baseline: 1.1363x; 1.0473x over previous
//
#include <hip/hip_runtime.h>
#include <math.h>

// B=4 graphs, N=256 nodes (128+128)/graph, F=256, L=3 layers.
// 8 launches: prep + 3x{hqk, al} + fin. Cost model (r2/r3/r5/r7 fits):
// dur = C(~100us harness fixed) + E(kernel exec) + n*~1.3us. So: few launches,
// wide grids, SHALLOW serial phase depth per kernel (r7's 4-deep chain lost).
// GEMMs: bf16 MFMA 16x16x32, one wave per 16x16 tile, operands L2-resident.

typedef __attribute__((ext_vector_type(8))) short short8;   // 8 bf16
typedef __attribute__((ext_vector_type(4))) float f32x4;
typedef unsigned short u16;
typedef unsigned int   u32;

__device__ __forceinline__ u16 f2bf(float f) {
    union { float f; u32 u; } v; v.f = f;
    u32 r = v.u + 0x7fffu + ((v.u >> 16) & 1u);     // RNE
    return (u16)(r >> 16);
}
__device__ __forceinline__ short8 ld8(const u16* p) {
    return __builtin_bit_cast(short8, *(const int4*)p);
}

// ---- P0: pack x (fp32+bf16) + transpose conv_w -> Wt + cast lin_w ----------
__global__ __launch_bounds__(256) void k_prep(
    const float* __restrict__ d0, const float* __restrict__ d1,
    const float* __restrict__ conv_w, const float* __restrict__ lin_w,
    float* __restrict__ x, u16* __restrict__ xb,
    u16* __restrict__ Wt, u16* __restrict__ lwb) {
    for (int i = blockIdx.x * 256 + threadIdx.x; i < 1048576; i += 262144) {
        if (i < 262144) {
            int node = i >> 8, f = i & 255, b = node >> 8, nl = node & 255;
            float v = (nl < 128) ? d0[b * 32768 + f * 128 + nl]
                                 : d1[b * 32768 + f * 128 + (nl - 128)];
            x[i] = v; xb[i] = f2bf(v);
        } else if (i < 655360) {
            int o = i - 262144;                     // 6 mats of 256x256
            int mat = o >> 16, rem = o & 65535, e = rem >> 8, f = rem & 255;
            Wt[o] = f2bf(conv_w[mat * 65536 + f * 256 + e]);
        } else {
            int o = i - 655360;
            lwb[o] = f2bf(lin_w[o]);
        }
    }
}

// ---- K1: BN-apply(prev) + H-GEMM -> Ht + qs/ks e-chunk partials ------------
// grid 256 = (64 m-tiles) x (4 e-groups); 256 thr (4 waves). [r5-proven]
__global__ __launch_bounds__(256, 1) void k_hqk(
    const float* __restrict__ xprev, const float* __restrict__ msg2,
    const float* __restrict__ sums, const float* __restrict__ sumsq,
    const float* __restrict__ bw, const float* __restrict__ bb,
    const u16* __restrict__ cwt,                 // [2][256 e][256 f]
    const float* __restrict__ cq, const float* __restrict__ ck,
    float* __restrict__ xcur, u16* __restrict__ xb, u16* __restrict__ Ht,
    float* __restrict__ qpart, float* __restrict__ kpart, int do_bn) {
    __shared__ __align__(16) u16 Asub[16 * 264];  // [16 nodes][256 f] bf16
    const int tid = threadIdx.x;
    const int mt = blockIdx.x >> 2, eg = blockIdx.x & 3;
    const int m0 = mt * 16;
    const int lane = tid & 63, widx = tid >> 6;
    const int row = lane & 15, kg = lane >> 4;

    float scale = 0.f, shift = 0.f;
    if (do_bn) {                                  // col = tid, redundant/block
        float s1 = 0.f, s2 = 0.f;
        #pragma unroll 8
        for (int c = 0; c < 64; ++c) { s1 += sums[c * 256 + tid]; s2 += sumsq[c * 256 + tid]; }
        float mu  = s1 * (1.f / 1024.f);
        float var = s2 * (1.f / 1024.f) - mu * mu;        // biased, as reference
        scale = bw[tid] * rsqrtf(var + 1e-5f);
        shift = bb[tid] - mu * scale;
    }
    #pragma unroll
    for (int r = 0; r < 16; ++r) {                // x_cur rows, col = tid
        int idx = (m0 + r) * 256 + tid;
        float v = xprev[idx];
        if (do_bn) v += msg2[idx] * scale + shift;
        u16 hb = f2bf(v);
        Asub[r * 264 + tid] = hb;
        if (do_bn && eg == 0) { xcur[idx] = v; xb[idx] = hb; }
    }
    __syncthreads();

    const int et = eg * 4 + widx, e0 = et * 16;   // e-tile 0..15
    const u16* B0 = cwt + (e0 + row) * 256 + kg * 8;
    const u16* B1 = B0 + 65536;
    const u16* Ap = &Asub[row * 264 + kg * 8];
    f32x4 acc0 = {0.f,0.f,0.f,0.f}, acc1 = {0.f,0.f,0.f,0.f};
    #pragma unroll
    for (int k0 = 0; k0 < 256; k0 += 32) {
        short8 a = ld8(Ap + k0);
        acc0 = __builtin_amdgcn_mfma_f32_16x16x32_bf16(a, ld8(B0 + k0), acc0, 0, 0, 0);
        acc1 = __builtin_amdgcn_mfma_f32_16x16x32_bf16(a, ld8(B1 + k0), acc1, 0, 0, 0);
    }
    // D: col(lane&15)=e, row(kg*4+c)=node -> store transposed Ht[r][e][node]
    ushort4 o0, o1;
    o0.x = f2bf(acc0[0]); o0.y = f2bf(acc0[1]); o0.z = f2bf(acc0[2]); o0.w = f2bf(acc0[3]);
    o1.x = f2bf(acc1[0]); o1.y = f2bf(acc1[1]); o1.z = f2bf(acc1[2]); o1.w = f2bf(acc1[3]);
    *(ushort4*)(Ht + (e0 + row) * 1024 + m0 + kg * 4) = o0;
    *(ushort4*)(Ht + 262144 + (e0 + row) * 1024 + m0 + kg * 4) = o1;
    // qs/ks partials over this tile's 16 e's
    float qe = cq[e0 + row], ke = ck[e0 + row];
    float pq0[4], pk0[4], pq1[4], pk1[4];
    #pragma unroll
    for (int c = 0; c < 4; ++c) {
        pq0[c] = acc0[c] * qe; pk0[c] = acc0[c] * ke;
        pq1[c] = acc1[c] * qe; pk1[c] = acc1[c] * ke;
    }
    #pragma unroll
    for (int off = 1; off < 16; off <<= 1) {
        #pragma unroll
        for (int c = 0; c < 4; ++c) {
            pq0[c] += __shfl_xor(pq0[c], off);
            pk0[c] += __shfl_xor(pk0[c], off);
            pq1[c] += __shfl_xor(pq1[c], off);
            pk1[c] += __shfl_xor(pk1[c], off);
        }
    }
    if (row == 0) {
        float4 a4 = {pq0[0], pq0[1], pq0[2], pq0[3]};
        float4 b4 = {pk0[0], pk0[1], pk0[2], pk0[3]};
        float4 c4 = {pq1[0], pq1[1], pq1[2], pq1[3]};
        float4 d4 = {pk1[0], pk1[1], pk1[2], pk1[3]};
        *(float4*)&qpart[et * 1024 + m0 + kg * 4] = a4;
        *(float4*)&kpart[et * 1024 + m0 + kg * 4] = b4;
        *(float4*)&qpart[(16 + et) * 1024 + m0 + kg * 4] = c4;
        *(float4*)&kpart[(16 + et) * 1024 + m0 + kg * 4] = d4;
    }
}

// ---- K2: alpha + full attn GEMM (msg1 in LDS) + lin (64 n-cols) ------------
// grid 256 = (64 dst-tiles) x (4 ng); 256 thr (4 waves). attn phase is x4
// redundant across ng (~32 extra MFMAs/block — cheap); msg1 never hits global.
__global__ __launch_bounds__(256, 1) void k_al(
    const float* __restrict__ qpart, const float* __restrict__ kpart,
    const u16* __restrict__ Ht, const float* __restrict__ cb,
    const u16* __restrict__ xb, const u16* __restrict__ lwp,
    const float* __restrict__ lb,
    float* __restrict__ msg2, float* __restrict__ sums, float* __restrict__ sumsq) {
    __shared__ __align__(16) u16 Atile[16 * 264]; // alpha bf16 [16 dst][256 src]
    __shared__ __align__(16) u16 M1[16 * 264];    // msg1 bf16 [16 dst][256 e]
    __shared__ float ksl[2][256];
    __shared__ float qsl[2][16];
    __shared__ __align__(16) float T[4][16 * 20];
    const int tid = threadIdx.x;
    const int mt = blockIdx.x >> 2, ng = blockIdx.x & 3;
    const int m0 = mt * 16;
    const int g = mt >> 4, a = (mt >> 3) & 1;
    const int lane = tid & 63, w = tid >> 6;
    const int row = lane & 15, kg = lane >> 4;

    {   // stage ks/qs (sum 16 e-chunk partials)
        float k0s = 0.f, k1s = 0.f;
        #pragma unroll
        for (int c = 0; c < 16; ++c) {
            k0s += kpart[c * 1024 + g * 256 + tid];
            k1s += kpart[(16 + c) * 1024 + g * 256 + tid];
        }
        ksl[0][tid] = k0s; ksl[1][tid] = k1s;
    }
    if (tid < 32) {
        int rel = tid >> 4, r = tid & 15;
        float q = 0.f;
        #pragma unroll
        for (int c = 0; c < 16; ++c) q += qpart[(rel * 16 + c) * 1024 + m0 + r];
        qsl[rel][r] = q;
    }
    __syncthreads();
    {   // softmax: thread = (dst r = tid>>4, src chunk j = tid&15)
        const int r = tid >> 4, j = tid & 15;
        const int dl = (m0 + r) & 255;
        const int s0 = j * 16;
        const int rel = ((s0 >> 7) == a) ? 0 : 1; // chunk never crosses 128
        float qv = qsl[rel][r];
        float l[16], mx = -1e30f;
        #pragma unroll
        for (int i2 = 0; i2 < 16; ++i2) {
            float v = qv + ksl[rel][s0 + i2];
            v = (v >= 0.f) ? v : 0.2f * v;        // leaky_relu 0.2
            if (s0 + i2 == dl) v = -1e30f;        // no self-loop
            l[i2] = v; mx = fmaxf(mx, v);
        }
        #pragma unroll
        for (int off = 1; off < 16; off <<= 1) mx = fmaxf(mx, __shfl_xor(mx, off));
        float s = 0.f;
        #pragma unroll
        for (int i2 = 0; i2 < 16; ++i2) { l[i2] = __expf(l[i2] - mx); s += l[i2]; }
        #pragma unroll
        for (int off = 1; off < 16; off <<= 1) s += __shfl_xor(s, off);
        float inv = 1.f / (s + 1e-16f);
        #pragma unroll
        for (int i2 = 0; i2 < 16; i2 += 2) {
            u32 p = (u32)f2bf(l[i2] * inv) | ((u32)f2bf(l[i2 + 1] * inv) << 16);
            *(u32*)&Atile[r * 264 + s0 + i2] = p;
        }
    }
    __syncthreads();
    // attn GEMM: all 256 e's per block (wave w does e-tiles w*4..w*4+3)
    const u16* Ap = &Atile[row * 264 + kg * 8];
    #pragma unroll
    for (int it = 0; it < 4; ++it) {
        const int e0 = (w * 4 + it) * 16;
        f32x4 acc = {0.f,0.f,0.f,0.f};
        #pragma unroll
        for (int k0 = 0; k0 < 256; k0 += 32) {
            const int rel = (((k0 >> 7) & 1) == a) ? 0 : 1;   // tile-uniform
            const u16* B = Ht + rel * 262144 + (e0 + row) * 1024 + g * 256 + k0 + kg * 8;
            acc = __builtin_amdgcn_mfma_f32_16x16x32_bf16(ld8(Ap + k0), ld8(B), acc, 0, 0, 0);
        }
        float bias = cb[e0 + row];
        #pragma unroll
        for (int c = 0; c < 4; ++c)   // D: col=e (e0+row), regs = dst (kg*4+c)
            M1[(kg * 4 + c) * 264 + e0 + row] = f2bf(fmaxf(acc[c] + bias, 0.f));
    }
    __syncthreads();
    // lin GEMM: msg2 = [xb | msg1] @ lw^T + lb ; BN column partials
    {
        const int n0 = ng * 64 + w * 16;
        const u16* A0 = xb + (m0 + row) * 256 + kg * 8;
        const u16* A1 = &M1[row * 264 + kg * 8];
        const u16* B  = lwp + (n0 + row) * 512 + kg * 8;
        f32x4 acc = {0.f,0.f,0.f,0.f};
        #pragma unroll
        for (int k0 = 0; k0 < 512; k0 += 32) {
            short8 av = (k0 < 256) ? ld8(A0 + k0) : ld8(A1 + (k0 - 256));
            acc = __builtin_amdgcn_mfma_f32_16x16x32_bf16(av, ld8(B + k0), acc, 0, 0, 0);
        }
        float bias = lb[n0 + row];
        float v0 = acc[0] + bias, v1 = acc[1] + bias, v2 = acc[2] + bias, v3 = acc[3] + bias;
        float s1 = v0 + v1 + v2 + v3;
        float s2 = v0 * v0 + v1 * v1 + v2 * v2 + v3 * v3;
        s1 += __shfl_xor(s1, 16); s1 += __shfl_xor(s1, 32);
        s2 += __shfl_xor(s2, 16); s2 += __shfl_xor(s2, 32);
        if (lane < 16) {          // lane = n col within tile
            sums [mt * 256 + n0 + lane] = s1;
            sumsq[mt * 256 + n0 + lane] = s2;
        }
        float* Tw = &T[w][0];     // wave-local transpose slice
        Tw[(kg * 4 + 0) * 20 + row] = v0;
        Tw[(kg * 4 + 1) * 20 + row] = v1;
        Tw[(kg * 4 + 2) * 20 + row] = v2;
        Tw[(kg * 4 + 3) * 20 + row] = v3;
        float4 vv = *(float4*)&Tw[row * 20 + kg * 4];
        *(float4*)(msg2 + (m0 + row) * 256 + n0 + kg * 4) = vv;
    }
}

// ---- K_fin: final BN + residual + unpack to [B,F,N0]|[B,F,N1] --------------
__global__ __launch_bounds__(256) void k_fin(
    const float* __restrict__ x2, const float* __restrict__ msg2,
    const float* __restrict__ sums, const float* __restrict__ sumsq,
    const float* __restrict__ bw, const float* __restrict__ bb,
    float* __restrict__ out) {
    const int blk = blockIdx.x, t = threadIdx.x;
    float s1 = 0.f, s2 = 0.f;
    #pragma unroll 8
    for (int c = 0; c < 64; ++c) { s1 += sums[c * 256 + t]; s2 += sumsq[c * 256 + t]; }
    float mu  = s1 * (1.f / 1024.f);
    float var = s2 * (1.f / 1024.f) - mu * mu;
    float scale = bw[t] * rsqrtf(var + 1e-5f);
    float shift = bb[t] - mu * scale;
    #pragma unroll
    for (int j = 0; j < 4; ++j) {
        int node = blk * 4 + j;
        int idx = node * 256 + t;
        float v = x2[idx] + msg2[idx] * scale + shift;
        int b = node >> 8, nl = node & 255, half = nl >> 7, n = nl & 127;
        out[half * 131072 + b * 32768 + t * 128 + n] = v;
    }
}

// ----------------------------------------------------------------------------
extern "C" void kernel_launch(void* const* d_in, const int* in_sizes, int n_in,
                              void* d_out, int out_size, void* d_ws, size_t ws_size,
                              hipStream_t stream) {
    const float* desc0  = (const float*)d_in[0];
    const float* desc1  = (const float*)d_in[1];
    const float* conv_w = (const float*)d_in[2];
    const float* conv_q = (const float*)d_in[3];
    const float* conv_k = (const float*)d_in[4];
    const float* conv_b = (const float*)d_in[5];
    const float* lin_w  = (const float*)d_in[6];
    const float* lin_b  = (const float*)d_in[7];
    const float* bn_w   = (const float*)d_in[8];
    const float* bn_b   = (const float*)d_in[9];
    float* out = (float*)d_out;

    char* p = (char*)d_ws;
    float* x0     = (float*)p; p += 1048576;
    float* x1     = (float*)p; p += 1048576;
    u16*   xb     = (u16*)p;   p += 524288;
    u16*   Wt     = (u16*)p;   p += 786432;    // [3][2][256e][256f]
    u16*   lwb    = (u16*)p;   p += 786432;
    u16*   Ht     = (u16*)p;   p += 1048576;   // [2][256e][1024node]
    float* qpart  = (float*)p; p += 131072;    // [32][1024]
    float* kpart  = (float*)p; p += 131072;
    float* msg2   = (float*)p; p += 1048576;
    float* sums   = (float*)p; p += 65536;     // [64][256]
    float* sumsq  = (float*)p; p += 65536;

    k_prep<<<1024, 256, 0, stream>>>(desc0, desc1, conv_w, lin_w, x0, xb, Wt, lwb);

    // layer i reads xs[i]; writes xs[i+1] only when do_bn (i>0). Layer 0
    // leaves x unchanged, so layer 1 must read x0 again.
    float* xs[4] = {x0, x0, x1, x0};
    for (int i = 0; i < 3; ++i) {
        const u16*   cwt = Wt + i * 131072;
        const u16*   lwp = lwb + i * 131072;
        const float* cq = conv_q + i * 256;
        const float* ck = conv_k + i * 256;
        const float* cb = conv_b + i * 256;
        const float* lb = lin_b + i * 256;
        const float* bwp = bn_w + (i ? (i - 1) * 256 : 0);   // prev-layer BN
        const float* bbp = bn_b + (i ? (i - 1) * 256 : 0);

        k_hqk<<<256, 256, 0, stream>>>(xs[i], msg2, sums, sumsq, bwp, bbp,
                                       cwt, cq, ck, xs[i + 1], xb, Ht,
                                       qpart, kpart, i > 0 ? 1 : 0);
        k_al<<<256, 256, 0, stream>>>(qpart, kpart, Ht, cb, xb, lwp, lb,
                                      msg2, sums, sumsq);
    }

    k_fin<<<256, 256, 0, stream>>>(xs[3], msg2, sums, sumsq,
                                   bn_w + 512, bn_b + 512, out);
}